// Round 2
// baseline (147.126 us; speedup 1.0000x reference)
//
#include <hip/hip_runtime.h>

typedef float f32x2 __attribute__((ext_vector_type(2)));
typedef float f32x4 __attribute__((ext_vector_type(4)));

#define PAD 3
#define HH 320
#define WW 1024
#define BB 8
#define TH 32
#define TW 64
#define HALO_H (TH + 2*PAD)   // 38
#define LDS_W  72             // 4 left halo + 64 + 4 right halo, 16B-aligned columns
#define NF4    (LDS_W/4)      // 18 float4 per staged row
#define NPOS   (HALO_H * NF4) // 684 float4 positions per plane
#define RPW 4                 // rows per wave (32 rows / 8 waves)
#define NWAVES 8
#define NTHREADS (NWAVES * 64)

#define NIN ((HH - 2*PAD) * (WW - 2*PAD))
#define OUT_SCALE (1.0 / (49.0 * (double)BB * (double)HH * (double)WW))
#define C0 ((float)(48.0 * (double)BB * (double)NIN * OUT_SCALE))
#define NEG_SCALE ((float)(-0.1 * OUT_SCALE))

// keep a value pinned in a VGPR (defeat LDS-load rematerialization)
#define KEEP(v) asm("" : "+v"(v))

__device__ __forceinline__ f32x2 mk2(float a, float b) { f32x2 r; r.x = a; r.y = b; return r; }
__device__ __forceinline__ f32x2 sp2(float a)          { f32x2 r; r.x = a; r.y = a; return r; }
__device__ __forceinline__ f32x2 fma2(f32x2 a, f32x2 b, f32x2 c) {
    return __builtin_elementwise_fma(a, b, c);
}

// Two offsets at once (packed). Exact algebra:
//   t = dx/sqrt(ax) - dy/sqrt(ay),  ax=0.81+dx^2, ay=0.81+dy^2
//   t^2 = s*(s*A - 2*dx*dy),  s=rsq(ax*ay),  A=dx^2*ay+dy^2*ax
//   contribution = w1/(0.1+t1^2) + w2/(0.1+t2^2) = rcp(b1*b2)*(w1*b2 + w2*b1)
// INTERIOR: w==2 for every pair -> cross = b1+b2, the factor 2 applied once at end.
template<bool INTERIOR>
__device__ __forceinline__ void pair2(f32x2 nx, f32x2 ny, f32x2 cx2, f32x2 cy2,
                                      f32x2 w2, float& acc)
{
    f32x2 dx  = nx - cx2;
    f32x2 dy  = ny - cy2;
    f32x2 dx2 = dx * dx;
    f32x2 dy2 = dy * dy;
    f32x2 ax  = dx2 + sp2(0.81f);
    f32x2 ay  = dy2 + sp2(0.81f);
    f32x2 P   = ax * ay;
    f32x2 s   = mk2(__builtin_amdgcn_rsqf(P.x), __builtin_amdgcn_rsqf(P.y));
    f32x2 A   = fma2(dx2, ay, dy2 * ax);
    f32x2 h   = dx * dy;
    f32x2 inner = fma2(s, A, h * sp2(-2.0f));
    f32x2 t2  = s * inner;
    f32x2 den = t2 + sp2(0.1f);
    float ip    = __builtin_amdgcn_rcpf(den.x * den.y);
    float cross;
    if constexpr (INTERIOR) cross = den.x + den.y;
    else                    cross = fmaf(w2.x, den.y, w2.y * den.x);
    acc = fmaf(ip, cross, acc);
}

template<bool INTERIOR>
__device__ __forceinline__ float compute_rows(
    const float (&sIx)[HALO_H][LDS_W], const float (&sIy)[HALO_H][LDS_W],
    int tile_i, int tile_j, int tx, int wv)
{
    // ---- per-lane column-interior flags (border blocks only) ----
    float cO[7] = {};
    f32x2 cP0 = {}, cP1 = {}, cP2 = {}, cP3 = {};
    if constexpr (!INTERIOR) {
        const int gj = tile_j + tx;
        #pragma unroll
        for (int d = 0; d < 7; ++d) {
            int nj = gj + d - 3;
            cO[d] = (nj >= PAD && nj < WW - PAD) ? 1.0f : 0.0f;
        }
        cP0 = mk2(cO[0], cO[1]);   // dj = -3,-2
        cP1 = mk2(cO[2], cO[3]);   // dj = -1, 0
        cP2 = mk2(cO[4], cO[5]);   // dj = +1,+2
        cP3 = sp2(cO[6]);          // dj = +3 (leftover pairs)
    }

    // ---- rolling 4-row register window; this wave owns rows [li0, li0+4) ----
    const int li0 = wv * RPW;

    float wx[4][7], wy[4][7];
    #pragma unroll
    for (int r = 0; r < 3; ++r) {
        #pragma unroll
        for (int d = 0; d < 7; ++d) {
            float a = sIx[li0 + 3 + r][tx + 1 + d]; KEEP(a); wx[r][d] = a;
            float c = sIy[li0 + 3 + r][tx + 1 + d]; KEEP(c); wy[r][d] = c;
        }
    }

    float acc = 0.0f;

    #pragma unroll
    for (int iu = 0; iu < RPW; ++iu) {
        const int li = li0 + iu;
        const int gi = tile_i + li;
        const int snew = (iu + 3) & 3;
        #pragma unroll
        for (int d = 0; d < 7; ++d) {
            float a = sIx[li + 6][tx + 1 + d]; KEEP(a); wx[snew][d] = a;
            float c = sIy[li + 6][tx + 1 + d]; KEEP(c); wy[snew][d] = c;
        }

        float rin[4] = {};
        f32x2 mc2 = {};
        if constexpr (!INTERIOR) {
            #pragma unroll
            for (int di = 0; di < 4; ++di) {
                int ni = gi + di;
                rin[di] = (ni >= PAD && ni < HH - PAD) ? 1.0f : 0.0f;
            }
            mc2 = sp2(rin[0] * cO[3]);        // center-pixel mask
        }

        const int s0 = iu & 3;
        const f32x2 cx2 = sp2(wx[s0][3]);
        const f32x2 cy2 = sp2(wy[s0][3]);

        // di = 0, dj = +1,+2  (window cols 4,5)
        pair2<INTERIOR>(mk2(wx[s0][4], wx[s0][5]), mk2(wy[s0][4], wy[s0][5]),
              cx2, cy2, INTERIOR ? sp2(0.0f) : fma2(sp2(rin[0]), cP2, mc2), acc);

        // di = 1..3, dj = -3..+2 as three packed groups each
        #pragma unroll
        for (int di = 1; di <= 3; ++di) {
            const int s = (iu + di) & 3;
            const f32x2 rin2 = sp2(rin[di]);
            pair2<INTERIOR>(mk2(wx[s][0], wx[s][1]), mk2(wy[s][0], wy[s][1]),
                  cx2, cy2, INTERIOR ? sp2(0.0f) : fma2(rin2, cP0, mc2), acc);
            pair2<INTERIOR>(mk2(wx[s][2], wx[s][3]), mk2(wy[s][2], wy[s][3]),
                  cx2, cy2, INTERIOR ? sp2(0.0f) : fma2(rin2, cP1, mc2), acc);
            pair2<INTERIOR>(mk2(wx[s][4], wx[s][5]), mk2(wy[s][4], wy[s][5]),
                  cx2, cy2, INTERIOR ? sp2(0.0f) : fma2(rin2, cP2, mc2), acc);
        }

        // leftovers dj = +3 (col 6), packed across di: (0,1) and (2,3)
        {
            const int s1 = (iu + 1) & 3;
            const int s2 = (iu + 2) & 3;
            const int s3 = (iu + 3) & 3;
            pair2<INTERIOR>(mk2(wx[s0][6], wx[s1][6]), mk2(wy[s0][6], wy[s1][6]),
                  cx2, cy2, INTERIOR ? sp2(0.0f) : fma2(mk2(rin[0], rin[1]), cP3, mc2), acc);
            pair2<INTERIOR>(mk2(wx[s2][6], wx[s3][6]), mk2(wy[s2][6], wy[s3][6]),
                  cx2, cy2, INTERIOR ? sp2(0.0f) : fma2(mk2(rin[2], rin[3]), cP3, mc2), acc);
        }
    }

    return acc;
}

__global__ __launch_bounds__(NTHREADS, 8) void ternary_loss_kernel(
    const float* __restrict__ x, const float* __restrict__ y,
    float* __restrict__ out)
{
    __shared__ __align__(16) float sIx[HALO_H][LDS_W];
    __shared__ __align__(16) float sIy[HALO_H][LDS_W];
    __shared__ float wave_sums[NWAVES];

    const int tile_j = blockIdx.x * TW;
    const int tile_i = blockIdx.y * TH;
    const int b      = blockIdx.z;
    const int tx  = threadIdx.x;            // 0..63
    const int wv  = threadIdx.y;            // 0..7
    const int tid = wv * 64 + tx;

    const size_t PLANE = (size_t)HH * WW;
    const float* xb = x + (size_t)b * 3 * PLANE;
    const float* yb = y + (size_t)b * 3 * PLANE;

    // ---- stage intensity halo tile into LDS with aligned float4 loads ----
    for (int p = tid; p < NPOS; p += NTHREADS) {
        int r  = p / NF4;
        int c4 = p - r * NF4;
        int gi  = tile_i - PAD + r;
        int gj0 = tile_j - 4 + 4 * c4;
        f32x4 vx = {0.0f, 0.0f, 0.0f, 0.0f};
        f32x4 vy = {0.0f, 0.0f, 0.0f, 0.0f};
        if ((unsigned)gi < (unsigned)HH && (unsigned)gj0 < (unsigned)WW) {
            const float* px = xb + (size_t)gi * WW + gj0;
            f32x4 a0 = *(const f32x4*)(px);
            f32x4 a1 = *(const f32x4*)(px + PLANE);
            f32x4 a2 = *(const f32x4*)(px + 2 * PLANE);
            vx = (a0 + a1 + a2) * (1.0f / 3.0f);
            const float* py = yb + (size_t)gi * WW + gj0;
            f32x4 b0 = *(const f32x4*)(py);
            f32x4 b1 = *(const f32x4*)(py + PLANE);
            f32x4 b2 = *(const f32x4*)(py + 2 * PLANE);
            vy = (b0 + b1 + b2) * (1.0f / 3.0f);
        }
        *(f32x4*)&sIx[r][4 * c4] = vx;
        *(f32x4*)&sIy[r][4 * c4] = vy;
    }
    __syncthreads();

    // block-uniform interior test: every pair in this tile has weight 2
    const bool interior = (tile_i >= PAD) && (tile_i + TH + PAD <= HH - PAD)
                       && (tile_j >= 2*PAD) && (tile_j + TW + PAD <= WW - PAD);

    float acc;
    if (interior) acc = 2.0f * compute_rows<true >(sIx, sIy, tile_i, tile_j, tx, wv);
    else          acc =        compute_rows<false>(sIx, sIy, tile_i, tile_j, tx, wv);

    // ---- reduction: wave shuffle -> LDS across 8 waves -> one atomic ----
    #pragma unroll
    for (int off = 32; off > 0; off >>= 1)
        acc += __shfl_down(acc, off, 64);
    if (tx == 0) wave_sums[wv] = acc;
    __syncthreads();
    if (tid == 0) {
        float total = 0.0f;
        #pragma unroll
        for (int w = 0; w < NWAVES; ++w) total += wave_sums[w];
        total *= NEG_SCALE;
        if (blockIdx.x == 0 && blockIdx.y == 0 && blockIdx.z == 0)
            total += C0;                       // analytic  sum(w)*1  term, added once
        atomicAdd(out, total);
    }
}

extern "C" void kernel_launch(void* const* d_in, const int* in_sizes, int n_in,
                              void* d_out, int out_size, void* d_ws, size_t ws_size,
                              hipStream_t stream) {
    const float* x = (const float*)d_in[0];
    const float* y = (const float*)d_in[1];
    float* out = (float*)d_out;

    hipMemsetAsync(out, 0, sizeof(float), stream);

    dim3 grid(WW / TW, HH / TH, BB);   // 16 x 10 x 8 = 1280 blocks
    dim3 block(64, NWAVES, 1);
    ternary_loss_kernel<<<grid, block, 0, stream>>>(x, y, out);
}

// Round 3
// 115.936 us; speedup vs baseline: 1.2690x; 1.2690x over previous
//
#include <hip/hip_runtime.h>

typedef float f32x2 __attribute__((ext_vector_type(2)));
typedef float f32x4 __attribute__((ext_vector_type(4)));

#define PAD 3
#define HH 320
#define WW 1024
#define BB 8
#define TH 32
#define TW 64
#define HALO_H (TH + 2*PAD)   // 38
#define LDS_W  72             // 4 left halo + 64 + 4 right halo, 16B-aligned columns
#define NF4    (LDS_W/4)      // 18 float4 per staged row
#define NPOS   (HALO_H * NF4) // 684 float4 positions per plane
#define RPW 4                 // rows per wave (32 rows / 8 waves)
#define NWAVES 8
#define NTHREADS (NWAVES * 64)

#define NIN ((HH - 2*PAD) * (WW - 2*PAD))
#define OUT_SCALE (1.0 / (49.0 * (double)BB * (double)HH * (double)WW))
#define C0 ((float)(48.0 * (double)BB * (double)NIN * OUT_SCALE))
#define NEG_SCALE ((float)(-0.1 * OUT_SCALE))

// keep a value pinned in a VGPR (defeat LDS-load rematerialization)
#define KEEP(v) asm("" : "+v"(v))

__device__ __forceinline__ f32x2 mk2(float a, float b) { f32x2 r; r.x = a; r.y = b; return r; }
__device__ __forceinline__ f32x2 sp2(float a)          { f32x2 r; r.x = a; r.y = a; return r; }
__device__ __forceinline__ f32x2 fma2(f32x2 a, f32x2 b, f32x2 c) {
    return __builtin_elementwise_fma(a, b, c);
}

// Two offsets at once (packed). Exact algebra:
//   t = dx/sqrt(ax) - dy/sqrt(ay),  ax=0.81+dx^2, ay=0.81+dy^2
//   t^2 = s*(s*A - 2*dx*dy),  s=rsq(ax*ay),  A=dx^2*ay+dy^2*ax
//   contribution = w1/(0.1+t1^2) + w2/(0.1+t2^2) = rcp(b1*b2)*(w1*b2 + w2*b1)
// INTERIOR: w==2 for every pair -> cross = b1+b2, the factor 2 applied once at end.
template<bool INTERIOR>
__device__ __forceinline__ void pair2(f32x2 nx, f32x2 ny, f32x2 cx2, f32x2 cy2,
                                      f32x2 w2, float& acc)
{
    f32x2 dx  = nx - cx2;
    f32x2 dy  = ny - cy2;
    f32x2 dx2 = dx * dx;
    f32x2 dy2 = dy * dy;
    f32x2 ax  = dx2 + sp2(0.81f);
    f32x2 ay  = dy2 + sp2(0.81f);
    f32x2 P   = ax * ay;
    f32x2 s   = mk2(__builtin_amdgcn_rsqf(P.x), __builtin_amdgcn_rsqf(P.y));
    f32x2 A   = fma2(dx2, ay, dy2 * ax);
    f32x2 h   = dx * dy;
    f32x2 inner = fma2(s, A, h * sp2(-2.0f));
    f32x2 t2  = s * inner;
    f32x2 den = t2 + sp2(0.1f);
    float ip    = __builtin_amdgcn_rcpf(den.x * den.y);
    float cross;
    if constexpr (INTERIOR) cross = den.x + den.y;
    else                    cross = fmaf(w2.x, den.y, w2.y * den.x);
    acc = fmaf(ip, cross, acc);
}

template<bool INTERIOR>
__device__ __forceinline__ float compute_rows(
    const float (&sIx)[HALO_H][LDS_W], const float (&sIy)[HALO_H][LDS_W],
    int tile_i, int tile_j, int tx, int wv)
{
    // ---- per-lane column-interior flags (border blocks only) ----
    float cO[7] = {};
    f32x2 cP0 = {}, cP1 = {}, cP2 = {}, cP3 = {};
    if constexpr (!INTERIOR) {
        const int gj = tile_j + tx;
        #pragma unroll
        for (int d = 0; d < 7; ++d) {
            int nj = gj + d - 3;
            cO[d] = (nj >= PAD && nj < WW - PAD) ? 1.0f : 0.0f;
        }
        cP0 = mk2(cO[0], cO[1]);   // dj = -3,-2
        cP1 = mk2(cO[2], cO[3]);   // dj = -1, 0
        cP2 = mk2(cO[4], cO[5]);   // dj = +1,+2
        cP3 = sp2(cO[6]);          // dj = +3 (leftover pairs)
    }

    // ---- rolling 4-row register window; this wave owns rows [li0, li0+4) ----
    const int li0 = wv * RPW;

    float wx[4][7], wy[4][7];
    #pragma unroll
    for (int r = 0; r < 3; ++r) {
        #pragma unroll
        for (int d = 0; d < 7; ++d) {
            float a = sIx[li0 + 3 + r][tx + 1 + d]; KEEP(a); wx[r][d] = a;
            float c = sIy[li0 + 3 + r][tx + 1 + d]; KEEP(c); wy[r][d] = c;
        }
    }

    float acc = 0.0f;

    #pragma unroll
    for (int iu = 0; iu < RPW; ++iu) {
        const int li = li0 + iu;
        const int gi = tile_i + li;
        const int snew = (iu + 3) & 3;
        #pragma unroll
        for (int d = 0; d < 7; ++d) {
            float a = sIx[li + 6][tx + 1 + d]; KEEP(a); wx[snew][d] = a;
            float c = sIy[li + 6][tx + 1 + d]; KEEP(c); wy[snew][d] = c;
        }

        float rin[4] = {};
        f32x2 mc2 = {};
        if constexpr (!INTERIOR) {
            #pragma unroll
            for (int di = 0; di < 4; ++di) {
                int ni = gi + di;
                rin[di] = (ni >= PAD && ni < HH - PAD) ? 1.0f : 0.0f;
            }
            mc2 = sp2(rin[0] * cO[3]);        // center-pixel mask
        }

        const int s0 = iu & 3;
        const f32x2 cx2 = sp2(wx[s0][3]);
        const f32x2 cy2 = sp2(wy[s0][3]);

        // di = 0, dj = +1,+2  (window cols 4,5)
        pair2<INTERIOR>(mk2(wx[s0][4], wx[s0][5]), mk2(wy[s0][4], wy[s0][5]),
              cx2, cy2, INTERIOR ? sp2(0.0f) : fma2(sp2(rin[0]), cP2, mc2), acc);

        // di = 1..3, dj = -3..+2 as three packed groups each
        #pragma unroll
        for (int di = 1; di <= 3; ++di) {
            const int s = (iu + di) & 3;
            const f32x2 rin2 = sp2(rin[di]);
            pair2<INTERIOR>(mk2(wx[s][0], wx[s][1]), mk2(wy[s][0], wy[s][1]),
                  cx2, cy2, INTERIOR ? sp2(0.0f) : fma2(rin2, cP0, mc2), acc);
            pair2<INTERIOR>(mk2(wx[s][2], wx[s][3]), mk2(wy[s][2], wy[s][3]),
                  cx2, cy2, INTERIOR ? sp2(0.0f) : fma2(rin2, cP1, mc2), acc);
            pair2<INTERIOR>(mk2(wx[s][4], wx[s][5]), mk2(wy[s][4], wy[s][5]),
                  cx2, cy2, INTERIOR ? sp2(0.0f) : fma2(rin2, cP2, mc2), acc);
        }

        // leftovers dj = +3 (col 6), packed across di: (0,1) and (2,3)
        {
            const int s1 = (iu + 1) & 3;
            const int s2 = (iu + 2) & 3;
            const int s3 = (iu + 3) & 3;
            pair2<INTERIOR>(mk2(wx[s0][6], wx[s1][6]), mk2(wy[s0][6], wy[s1][6]),
                  cx2, cy2, INTERIOR ? sp2(0.0f) : fma2(mk2(rin[0], rin[1]), cP3, mc2), acc);
            pair2<INTERIOR>(mk2(wx[s2][6], wx[s3][6]), mk2(wy[s2][6], wy[s3][6]),
                  cx2, cy2, INTERIOR ? sp2(0.0f) : fma2(mk2(rin[2], rin[3]), cP3, mc2), acc);
        }
    }

    return acc;
}

// NOTE: min-waves arg = 4 (waves/EU), NOT 8.  Round-2's (512,8) capped the
// allocator at 32 VGPRs -> 56-float rolling window spilled to scratch
// (WRITE_SIZE 0.04 -> 74.9 MB).  (512,4) caps at 128; kernel needs ~60.
__global__ __launch_bounds__(NTHREADS, 4) void ternary_loss_kernel(
    const float* __restrict__ x, const float* __restrict__ y,
    float* __restrict__ out)
{
    __shared__ __align__(16) float sIx[HALO_H][LDS_W];
    __shared__ __align__(16) float sIy[HALO_H][LDS_W];
    __shared__ float wave_sums[NWAVES];

    const int tile_j = blockIdx.x * TW;
    const int tile_i = blockIdx.y * TH;
    const int b      = blockIdx.z;
    const int tx  = threadIdx.x;            // 0..63
    const int wv  = threadIdx.y;            // 0..7
    const int tid = wv * 64 + tx;

    const size_t PLANE = (size_t)HH * WW;
    const float* xb = x + (size_t)b * 3 * PLANE;
    const float* yb = y + (size_t)b * 3 * PLANE;

    // ---- stage intensity halo tile into LDS with aligned float4 loads ----
    for (int p = tid; p < NPOS; p += NTHREADS) {
        int r  = p / NF4;
        int c4 = p - r * NF4;
        int gi  = tile_i - PAD + r;
        int gj0 = tile_j - 4 + 4 * c4;
        f32x4 vx = {0.0f, 0.0f, 0.0f, 0.0f};
        f32x4 vy = {0.0f, 0.0f, 0.0f, 0.0f};
        if ((unsigned)gi < (unsigned)HH && (unsigned)gj0 < (unsigned)WW) {
            const float* px = xb + (size_t)gi * WW + gj0;
            f32x4 a0 = *(const f32x4*)(px);
            f32x4 a1 = *(const f32x4*)(px + PLANE);
            f32x4 a2 = *(const f32x4*)(px + 2 * PLANE);
            vx = (a0 + a1 + a2) * (1.0f / 3.0f);
            const float* py = yb + (size_t)gi * WW + gj0;
            f32x4 b0 = *(const f32x4*)(py);
            f32x4 b1 = *(const f32x4*)(py + PLANE);
            f32x4 b2 = *(const f32x4*)(py + 2 * PLANE);
            vy = (b0 + b1 + b2) * (1.0f / 3.0f);
        }
        *(f32x4*)&sIx[r][4 * c4] = vx;
        *(f32x4*)&sIy[r][4 * c4] = vy;
    }
    __syncthreads();

    // block-uniform interior test: every pair in this tile has weight 2
    const bool interior = (tile_i >= PAD) && (tile_i + TH + PAD <= HH - PAD)
                       && (tile_j >= 2*PAD) && (tile_j + TW + PAD <= WW - PAD);

    float acc;
    if (interior) acc = 2.0f * compute_rows<true >(sIx, sIy, tile_i, tile_j, tx, wv);
    else          acc =        compute_rows<false>(sIx, sIy, tile_i, tile_j, tx, wv);

    // ---- reduction: wave shuffle -> LDS across 8 waves -> one atomic ----
    #pragma unroll
    for (int off = 32; off > 0; off >>= 1)
        acc += __shfl_down(acc, off, 64);
    if (tx == 0) wave_sums[wv] = acc;
    __syncthreads();
    if (tid == 0) {
        float total = 0.0f;
        #pragma unroll
        for (int w = 0; w < NWAVES; ++w) total += wave_sums[w];
        total *= NEG_SCALE;
        if (blockIdx.x == 0 && blockIdx.y == 0 && blockIdx.z == 0)
            total += C0;                       // analytic  sum(w)*1  term, added once
        atomicAdd(out, total);
    }
}

extern "C" void kernel_launch(void* const* d_in, const int* in_sizes, int n_in,
                              void* d_out, int out_size, void* d_ws, size_t ws_size,
                              hipStream_t stream) {
    const float* x = (const float*)d_in[0];
    const float* y = (const float*)d_in[1];
    float* out = (float*)d_out;

    hipMemsetAsync(out, 0, sizeof(float), stream);

    dim3 grid(WW / TW, HH / TH, BB);   // 16 x 10 x 8 = 1280 blocks
    dim3 block(64, NWAVES, 1);
    ternary_loss_kernel<<<grid, block, 0, stream>>>(x, y, out);
}